// Round 1
// baseline (173.715 us; speedup 1.0000x reference)
//
#include <hip/hip_runtime.h>
#include <hip/hip_bf16.h>
#include <stdint.h>

#define HIDDEN 128
#define NUM_RADIAL 6
#define K_TOT 384

typedef __attribute__((ext_vector_type(8))) short bf16x8;
typedef __attribute__((ext_vector_type(4))) float f32x4;

__device__ __forceinline__ float silu_f(float x) {
    return x / (1.0f + __expf(-x));
}

// round-to-nearest-even f32 -> bf16
__device__ __forceinline__ unsigned short f2bf(float x) {
    union { float f; unsigned int u; } v; v.f = x;
    unsigned int r = v.u + 0x7fffu + ((v.u >> 16) & 1u);
    return (unsigned short)(r >> 16);
}

// async global->LDS, 16B per lane. LDS dest = wave-uniform base + lane*16.
__device__ __forceinline__ void async16(void* l, const void* g) {
    auto lds3 = (__attribute__((address_space(3))) unsigned int*)(uintptr_t)l;
    auto g1   = (const __attribute__((address_space(1))) unsigned int*)(uintptr_t)g;
    __builtin_amdgcn_global_load_lds(g1, lds3, 16, 0, 0);
}

// Build bf16 table[128][128] (VQ concat embedding) and Wt[o][k] = W[k][o] bf16.
__global__ void prep_tables(const int* __restrict__ code_idx,
                            const float* __restrict__ codebook,
                            const float* __restrict__ W,
                            unsigned short* __restrict__ tableB,   // [128][128]
                            unsigned short* __restrict__ WtB)      // [128][384]
{
    int gid = blockIdx.x * blockDim.x + threadIdx.x;
    if (gid < 128 * HIDDEN) {
        int t = gid >> 7, c = gid & 127;
        int sym = code_idx[t * 8 + (c >> 4)];
        tableB[gid] = f2bf(codebook[sym * 16 + (c & 15)]);
    } else {
        int id = gid - 128 * HIDDEN;          // 0 .. 49151, id = k*128 + o
        int o = id & 127, k = id >> 7;
        WtB[o * K_TOT + k] = f2bf(W[id]);     // coalesced read, transposed write
    }
}

// R = silu(rbf @ W_rbf + b_rbf), bf16, overlaid into d_out: row e occupies the
// first 256B of out-row e's 512B slot (stride 256 bf16 elems).
__global__ void prep_r(const float* __restrict__ rbf,
                       const float* __restrict__ W_rbf,
                       const float* __restrict__ b_rbf,
                       unsigned short* __restrict__ R)
{
    int gid = blockIdx.x * blockDim.x + threadIdx.x;
    int e = gid >> 7, o = gid & 127;
    float acc = b_rbf[o];
#pragma unroll
    for (int q = 0; q < NUM_RADIAL; ++q)
        acc += rbf[e * NUM_RADIAL + q] * W_rbf[q * HIDDEN + o];
    R[(size_t)e * 256 + o] = f2bf(silu_f(acc));
}

// out[e][o] = silu( h_i.W1 + h_j.W2 + r.W3 + b ), 128-edge tiles, bf16 MFMA.
__global__ __launch_bounds__(256, 2) void gemm_main(
    const int* __restrict__ x,
    const int* __restrict__ ei,
    const int* __restrict__ ej,
    const unsigned short* __restrict__ tableB,  // [128][128] bf16
    const unsigned short* __restrict__ WtB,     // [128][384] bf16 (W^T)
    const unsigned short* __restrict__ R,       // stride 256 overlay in d_out
    const float* __restrict__ bias,
    float* __restrict__ out)
{
    __shared__ __align__(16) unsigned char lds[32768];  // A: [0,16K)  B: [16K,32K)

    const int tid  = threadIdx.x;
    const int lane = tid & 63;
    const int w    = tid >> 6;
    const int e0   = blockIdx.x * 128;

    // logical chunk this lane fetches (xor-swizzle vs row&7 == lane>>3)
    const int co = (lane & 7) ^ (lane >> 3);

    // Per-thread staging row sources: row = w*32 + q*8 + (lane>>3)
    const unsigned short* srcAi[4];
    const unsigned short* srcAj[4];
    const unsigned short* srcR[4];
    const unsigned short* srcB[4];
#pragma unroll
    for (int q = 0; q < 4; ++q) {
        int row = w * 32 + q * 8 + (lane >> 3);
        int e   = e0 + row;
        int ti  = x[ei[e]];
        int tj  = x[ej[e]];
        srcAi[q] = tableB + ti * 128;
        srcAj[q] = tableB + tj * 128;
        srcR[q]  = R + (size_t)e * 256;
        srcB[q]  = WtB + row * K_TOT;
    }

    f32x4 acc[4][4] = {};

    const int wm = (w >> 1) * 64;
    const int wn = (w & 1) * 64;

#pragma unroll
    for (int kb = 0; kb < 6; ++kb) {
        __syncthreads();   // previous iter's LDS reads complete
#pragma unroll
        for (int q = 0; q < 4; ++q) {
            const unsigned short* ga =
                (kb < 2) ? srcAi[q] : (kb < 4) ? srcAj[q] : srcR[q];
            ga += (kb & 1) * 64 + co * 8;
            async16(lds + (w * 4 + q) * 1024, ga);
            const unsigned short* gb = srcB[q] + kb * 64 + co * 8;
            async16(lds + 16384 + (w * 4 + q) * 1024, gb);
        }
        __syncthreads();   // drains vmcnt -> staged data visible
#pragma unroll
        for (int ks = 0; ks < 2; ++ks) {
            bf16x8 af[4], bfv[4];
            const int quad = lane >> 4;
            const int pc = (ks * 4 + quad) ^ (lane & 7);  // swizzled chunk
#pragma unroll
            for (int mi = 0; mi < 4; ++mi) {
                int m = wm + mi * 16 + (lane & 15);
                af[mi] = *(const bf16x8*)(lds + m * 128 + pc * 16);
                int o = wn + mi * 16 + (lane & 15);
                bfv[mi] = *(const bf16x8*)(lds + 16384 + o * 128 + pc * 16);
            }
#pragma unroll
            for (int mi = 0; mi < 4; ++mi)
#pragma unroll
                for (int ni = 0; ni < 4; ++ni)
                    acc[mi][ni] = __builtin_amdgcn_mfma_f32_16x16x32_bf16(
                        af[mi], bfv[ni], acc[mi][ni], 0, 0, 0);
        }
    }

    // Epilogue: C/D layout col = lane&15, row = (lane>>4)*4 + reg
#pragma unroll
    for (int ni = 0; ni < 4; ++ni) {
        int n = wn + ni * 16 + (lane & 15);
        float bv = bias[n];
#pragma unroll
        for (int mi = 0; mi < 4; ++mi) {
#pragma unroll
            for (int r = 0; r < 4; ++r) {
                int m = wm + mi * 16 + (lane >> 4) * 4 + r;
                out[(size_t)(e0 + m) * HIDDEN + n] = silu_f(acc[mi][ni][r] + bv);
            }
        }
    }
}

extern "C" void kernel_launch(void* const* d_in, const int* in_sizes, int n_in,
                              void* d_out, int out_size, void* d_ws, size_t ws_size,
                              hipStream_t stream) {
    const int*   x        = (const int*)d_in[0];
    const float* rbf      = (const float*)d_in[1];
    const int*   ei       = (const int*)d_in[2];
    const int*   ej       = (const int*)d_in[3];
    const int*   code_idx = (const int*)d_in[4];
    const float* codebook = (const float*)d_in[5];
    const float* W_rbf    = (const float*)d_in[6];
    const float* b_rbf    = (const float*)d_in[7];
    const float* W        = (const float*)d_in[8];
    const float* b        = (const float*)d_in[9];
    float* out = (float*)d_out;

    const int nE = in_sizes[2];               // 160000

    if (ws_size < 131072) return;             // table(32K)+Wt(96K) scratch

    unsigned short* tableB = (unsigned short*)d_ws;            // 32 KB
    unsigned short* WtB    = tableB + 128 * HIDDEN;            // 96 KB
    unsigned short* R      = (unsigned short*)d_out;           // overlay, stride 256

    // table (16384) + Wt (49152) = 65536 elems -> 256 blocks x 256
    prep_tables<<<256, 256, 0, stream>>>(code_idx, codebook, W, tableB, WtB);
    // nE*128 threads
    prep_r<<<nE / 2, 256, 0, stream>>>(rbf, W_rbf, b_rbf, R);
    // one block per 128 edges
    gemm_main<<<nE / 128, 256, 0, stream>>>(x, ei, ej, tableB, WtB, R, b, out);
}

// Round 2
// 142.916 us; speedup vs baseline: 1.2155x; 1.2155x over previous
//
#include <hip/hip_runtime.h>
#include <hip/hip_bf16.h>
#include <stdint.h>

typedef __attribute__((ext_vector_type(8))) short bf16x8;
typedef __attribute__((ext_vector_type(4))) float f32x4;

__device__ __forceinline__ float silu_f(float x) {
    return x / (1.0f + __expf(-x));
}

// round-to-nearest-even f32 -> bf16
__device__ __forceinline__ unsigned short f2bf(float x) {
    union { float f; unsigned int u; } v; v.f = x;
    unsigned int r = v.u + 0x7fffu + ((v.u >> 16) & 1u);
    return (unsigned short)(r >> 16);
}
__device__ __forceinline__ float bf2f(unsigned short u) {
    union { unsigned int u; float f; } v; v.u = ((unsigned int)u) << 16;
    return v.f;
}

// async global->LDS, 16B per lane. LDS dest = wave-uniform base + lane*16.
__device__ __forceinline__ void async16(void* l, const void* g) {
    auto lds3 = (__attribute__((address_space(3))) unsigned int*)(uintptr_t)l;
    auto g1   = (const __attribute__((address_space(1))) unsigned int*)(uintptr_t)g;
    __builtin_amdgcn_global_load_lds(g1, lds3, 16, 0, 0);
}

// Precompute:
//   P1[t][o] = sum_k table[t][k] * W[k][o]       + b[o]   (bf16)
//   P2[t][o] = sum_k table[t][k] * W[128+k][o]            (bf16)
//   Wt3[o][k] = W[256+k][o]                               (bf16, transposed)
// where table[t][:] = concat of 8 codebook vectors per code_idx[t].
// Grid: 128 blocks (one per type t) x 256 threads.
__global__ void prep_P(const int* __restrict__ code_idx,
                       const float* __restrict__ codebook,
                       const float* __restrict__ W,
                       const float* __restrict__ b,
                       unsigned short* __restrict__ P1,
                       unsigned short* __restrict__ P2,
                       unsigned short* __restrict__ Wt3)
{
    __shared__ float trow[128];
    const int t = blockIdx.x, tid = threadIdx.x;
    if (tid < 128) {
        int sym = code_idx[t * 8 + (tid >> 4)];
        trow[tid] = codebook[sym * 16 + (tid & 15)];
    } else {
        int k = tid - 128;                       // 0..127
        Wt3[t * 128 + k] = f2bf(W[(256 + k) * 128 + t]);
    }
    __syncthreads();
    const int which = tid >> 7, o = tid & 127;
    const float* Wb = W + which * 16384;         // W[which*128 + k][o]
    float acc = which ? 0.0f : b[o];
#pragma unroll 8
    for (int k = 0; k < 128; ++k)
        acc += trow[k] * Wb[k * 128 + o];
    (which ? P2 : P1)[t * 128 + o] = f2bf(acc);
}

// Fused main: per block of 128 edges:
//   A-tile (LDS) = r = silu(rbf @ W_rbf + b_rbf) bf16, computed by VALU
//   B-tile (LDS) = Wt3 (K=128), async16-staged
//   C = A @ B^T via mfma, epilogue adds P1[x[i]] + P2[x[j]], silu, fp32 store.
__global__ __launch_bounds__(256, 2) void fused_main(
    const int* __restrict__ x,
    const float* __restrict__ rbf,
    const int* __restrict__ ei,
    const int* __restrict__ ej,
    const float* __restrict__ W_rbf,
    const float* __restrict__ b_rbf,
    const unsigned short* __restrict__ P1,
    const unsigned short* __restrict__ P2,
    const unsigned short* __restrict__ Wt3,
    float* __restrict__ out)
{
    __shared__ __align__(16) unsigned char lA[32768];  // r-tile [128 rows][256B], chunk-swizzled
    __shared__ __align__(16) unsigned char lB[32768];  // Wt3    [128 rows][256B], chunk-swizzled

    const int tid  = threadIdx.x;
    const int lane = tid & 63;
    const int w    = tid >> 6;
    const int e0   = blockIdx.x * 128;

    // ---- stage B: Wt3 -> lB, physical chunk p holds logical chunk j = p ^ (o&7)
    {
        const int ri = lane >> 4;     // row within 4-row group
        const int ch = lane & 15;     // physical chunk this lane fills
#pragma unroll
        for (int rr = 0; rr < 8; ++rr) {
            int g = w * 8 + rr;       // 4-row group 0..31
            int o = g * 4 + ri;
            int j = ch ^ (o & 7);     // logical chunk to fetch
            async16(lB + g * 1024, Wt3 + o * 128 + j * 8);
        }
    }

    // ---- compute r-tile into lA: thread -> cols [j16*8, +8), edges [gg*8, +8)
    {
        const int j16 = tid & 15;     // col chunk 0..15
        const int gg  = tid >> 4;     // edge group 0..15
        const int cb  = j16 * 8;
        float wr[6][8];
#pragma unroll
        for (int q = 0; q < 6; ++q) {
            const float4* p = (const float4*)(W_rbf + q * 128 + cb);
            float4 a = p[0], c = p[1];
            wr[q][0]=a.x; wr[q][1]=a.y; wr[q][2]=a.z; wr[q][3]=a.w;
            wr[q][4]=c.x; wr[q][5]=c.y; wr[q][6]=c.z; wr[q][7]=c.w;
        }
        float br[8];
        {
            const float4* p = (const float4*)(b_rbf + cb);
            float4 a = p[0], c = p[1];
            br[0]=a.x; br[1]=a.y; br[2]=a.z; br[3]=a.w;
            br[4]=c.x; br[5]=c.y; br[6]=c.z; br[7]=c.w;
        }
#pragma unroll
        for (int i = 0; i < 8; ++i) {
            int m = gg * 8 + i;
            const float* rr = rbf + (size_t)(e0 + m) * 6;
            float f0=rr[0], f1=rr[1], f2=rr[2], f3=rr[3], f4=rr[4], f5=rr[5];
            bf16x8 pk;
#pragma unroll
            for (int c = 0; c < 8; ++c) {
                float acc = br[c] + f0*wr[0][c] + f1*wr[1][c] + f2*wr[2][c]
                                  + f3*wr[3][c] + f4*wr[4][c] + f5*wr[5][c];
                pk[c] = (short)f2bf(silu_f(acc));
            }
            int p = j16 ^ (m & 7);
            *(bf16x8*)(lA + m * 256 + p * 16) = pk;
        }
    }

    __syncthreads();   // drains async16 (vmcnt) + LDS writes

    // ---- MFMA: 64x64 tile per wave, K=128
    f32x4 acc[4][4] = {};
    const int wm = (w >> 1) * 64, wn = (w & 1) * 64;
    const int quad = lane >> 4, l15 = lane & 15, l7 = lane & 7;
#pragma unroll
    for (int ks = 0; ks < 4; ++ks) {
        const int j = ks * 4 + quad;          // logical k-chunk 0..15
        const int p = j ^ l7;                 // physical chunk (m&7 == l7)
        bf16x8 af[4], bfv[4];
#pragma unroll
        for (int mi = 0; mi < 4; ++mi) {
            int m = wm + mi * 16 + l15;
            af[mi]  = *(const bf16x8*)(lA + m * 256 + p * 16);
            int o = wn + mi * 16 + l15;
            bfv[mi] = *(const bf16x8*)(lB + o * 256 + p * 16);
        }
#pragma unroll
        for (int mi = 0; mi < 4; ++mi)
#pragma unroll
            for (int ni = 0; ni < 4; ++ni)
                acc[mi][ni] = __builtin_amdgcn_mfma_f32_16x16x32_bf16(
                    af[mi], bfv[ni], acc[mi][ni], 0, 0, 0);
    }

    // ---- epilogue: + P1[ti] + P2[tj], silu, store fp32
#pragma unroll
    for (int mi = 0; mi < 4; ++mi) {
#pragma unroll
        for (int r = 0; r < 4; ++r) {
            int m = wm + mi * 16 + quad * 4 + r;
            int e = e0 + m;
            int ti = x[ei[e]], tj = x[ej[e]];
            const unsigned short* p1r = P1 + ti * 128;
            const unsigned short* p2r = P2 + tj * 128;
#pragma unroll
            for (int ni = 0; ni < 4; ++ni) {
                int o = wn + ni * 16 + l15;
                float v = acc[mi][ni][r] + bf2f(p1r[o]) + bf2f(p2r[o]);
                out[(size_t)e * 128 + o] = silu_f(v);
            }
        }
    }
}

extern "C" void kernel_launch(void* const* d_in, const int* in_sizes, int n_in,
                              void* d_out, int out_size, void* d_ws, size_t ws_size,
                              hipStream_t stream) {
    const int*   x        = (const int*)d_in[0];
    const float* rbf      = (const float*)d_in[1];
    const int*   ei       = (const int*)d_in[2];
    const int*   ej       = (const int*)d_in[3];
    const int*   code_idx = (const int*)d_in[4];
    const float* codebook = (const float*)d_in[5];
    const float* W_rbf    = (const float*)d_in[6];
    const float* b_rbf    = (const float*)d_in[7];
    const float* W        = (const float*)d_in[8];
    const float* b        = (const float*)d_in[9];
    float* out = (float*)d_out;

    const int nE = in_sizes[2];                   // 160000

    if (ws_size < 98304) return;                  // P1 + P2 + Wt3, bf16
    unsigned short* P1  = (unsigned short*)d_ws;  // 32 KB
    unsigned short* P2  = P1 + 16384;             // 32 KB
    unsigned short* Wt3 = P2 + 16384;             // 32 KB

    prep_P<<<128, 256, 0, stream>>>(code_idx, codebook, W, b, P1, P2, Wt3);
    fused_main<<<nE / 128, 256, 0, stream>>>(x, rbf, ei, ej, W_rbf, b_rbf,
                                             P1, P2, Wt3, out);
}

// Round 3
// 132.936 us; speedup vs baseline: 1.3068x; 1.0751x over previous
//
#include <hip/hip_runtime.h>
#include <hip/hip_bf16.h>
#include <stdint.h>

typedef __attribute__((ext_vector_type(8))) short bf16x8;
typedef __attribute__((ext_vector_type(4))) float f32x4;

__device__ __forceinline__ float silu_f(float x) {
    return x * __builtin_amdgcn_rcpf(1.0f + __expf(-x));
}

// round-to-nearest-even f32 -> bf16
__device__ __forceinline__ unsigned short f2bf(float x) {
    union { float f; unsigned int u; } v; v.f = x;
    unsigned int r = v.u + 0x7fffu + ((v.u >> 16) & 1u);
    return (unsigned short)(r >> 16);
}
__device__ __forceinline__ float bf2f(unsigned short u) {
    union { unsigned int u; float f; } v; v.u = ((unsigned int)u) << 16;
    return v.f;
}

// async global->LDS, 16B per lane. LDS dest = wave-uniform base + lane*16.
__device__ __forceinline__ void async16(void* l, const void* g) {
    auto lds3 = (__attribute__((address_space(3))) unsigned int*)(uintptr_t)l;
    auto g1   = (const __attribute__((address_space(1))) unsigned int*)(uintptr_t)g;
    __builtin_amdgcn_global_load_lds(g1, lds3, 16, 0, 0);
}

// Precompute:
//   P1[t][o] = sum_k table[t][k] * W[k][o]       + b[o]   (bf16)
//   P2[t][o] = sum_k table[t][k] * W[128+k][o]            (bf16)
//   Wt3[o][k] = W[256+k][o]                               (bf16, transposed)
__global__ void prep_P(const int* __restrict__ code_idx,
                       const float* __restrict__ codebook,
                       const float* __restrict__ W,
                       const float* __restrict__ b,
                       unsigned short* __restrict__ P1,
                       unsigned short* __restrict__ P2,
                       unsigned short* __restrict__ Wt3)
{
    __shared__ float trow[128];
    const int t = blockIdx.x, tid = threadIdx.x;
    if (tid < 128) {
        int sym = code_idx[t * 8 + (tid >> 4)];
        trow[tid] = codebook[sym * 16 + (tid & 15)];
    } else {
        int k = tid - 128;                       // 0..127
        Wt3[t * 128 + k] = f2bf(W[(256 + k) * 128 + t]);
    }
    __syncthreads();
    const int which = tid >> 7, o = tid & 127;
    const float* Wb = W + which * 16384;
    float acc = which ? 0.0f : b[o];
#pragma unroll 8
    for (int k = 0; k < 128; ++k)
        acc += trow[k] * Wb[k * 128 + o];
    (which ? P2 : P1)[t * 128 + o] = f2bf(acc);
}

// Fused main, 64 edges per block, 256 threads (4 waves, 32x64 C-tile each):
//   lB = Wt3 (128x128 bf16, K=128), async16-staged, chunk-swizzled
//   lR = rbf tile (64 x 24B), async16-staged
//   lA = r = silu(rbf @ W_rbf + b_rbf) bf16, VALU-computed from lR
//   C = A @ B^T via mfma; epilogue adds register-prefetched P1[x_i]+P2[x_j].
__global__ __launch_bounds__(256, 3) void fused_main(
    const int* __restrict__ x,
    const float* __restrict__ rbf,
    const int* __restrict__ ei,
    const int* __restrict__ ej,
    const float* __restrict__ W_rbf,
    const float* __restrict__ b_rbf,
    const unsigned short* __restrict__ P1,
    const unsigned short* __restrict__ P2,
    const unsigned short* __restrict__ Wt3,
    float* __restrict__ out)
{
    __shared__ __align__(16) unsigned char lB[32768];  // Wt3 [128 rows][256B]
    __shared__ __align__(16) unsigned char lA[16384];  // r   [64 rows][256B]
    __shared__ __align__(16) unsigned char lR[1536];   // rbf [64 rows][24B]

    const int tid  = threadIdx.x;
    const int lane = tid & 63;
    const int w    = tid >> 6;
    const int e0   = blockIdx.x * 64;

    const int quad = lane >> 4, l15 = lane & 15;
    const int wm = (w >> 1) * 32, wn = (w & 1) * 64;

    // ---- phase 0: async stages + index chase ----
    {   // B: physical chunk ch holds logical chunk ch ^ (o&7)
        const int ri = lane >> 4, ch = lane & 15;
#pragma unroll
        for (int rr = 0; rr < 8; ++rr) {
            int g = w * 8 + rr;           // 4-row group 0..31
            int o = g * 4 + ri;
            int j = ch ^ (o & 7);
            async16(lB + g * 1024, Wt3 + o * 128 + j * 8);
        }
    }
    // rbf tile: 1536B contiguous
    if (w == 0)
        async16(lR, (const unsigned char*)rbf + (size_t)e0 * 24 + lane * 16);
    else if (w == 1 && lane < 32)
        async16(lR + 1024, (const unsigned char*)rbf + (size_t)e0 * 24 + 1024 + lane * 16);

    // epilogue row indices: 8 rows per thread, chase x[ei[e]], x[ej[e]] now
    int ti[8], tj[8];
#pragma unroll
    for (int mi = 0; mi < 2; ++mi)
#pragma unroll
        for (int r = 0; r < 4; ++r) {
            int m = wm + mi * 16 + quad * 4 + r;
            int e = e0 + m;
            ti[mi * 4 + r] = x[ei[e]];
            tj[mi * 4 + r] = x[ej[e]];
        }

    // r-weights (L2-hot, identical for all blocks)
    const int j16 = tid & 15, gg = tid >> 4, cb = j16 * 8;
    float wr[6][8], br[8];
#pragma unroll
    for (int q = 0; q < 6; ++q) {
        const float4* p = (const float4*)(W_rbf + q * 128 + cb);
        float4 a = p[0], c = p[1];
        wr[q][0]=a.x; wr[q][1]=a.y; wr[q][2]=a.z; wr[q][3]=a.w;
        wr[q][4]=c.x; wr[q][5]=c.y; wr[q][6]=c.z; wr[q][7]=c.w;
    }
    {
        const float4* p = (const float4*)(b_rbf + cb);
        float4 a = p[0], c = p[1];
        br[0]=a.x; br[1]=a.y; br[2]=a.z; br[3]=a.w;
        br[4]=c.x; br[5]=c.y; br[6]=c.z; br[7]=c.w;
    }

    __syncthreads();   // drains async16 (B + rbf in LDS)

    // ---- phase 1: r-compute from lR -> lA (4 edges x 8 cols per thread) ----
#pragma unroll
    for (int i = 0; i < 4; ++i) {
        int m = gg * 4 + i;
        const float* rr_ = (const float*)(lR + m * 24);
        float f0 = rr_[0], f1 = rr_[1], f2 = rr_[2],
              f3 = rr_[3], f4 = rr_[4], f5 = rr_[5];
        bf16x8 pk;
#pragma unroll
        for (int c = 0; c < 8; ++c) {
            float a = br[c] + f0*wr[0][c] + f1*wr[1][c] + f2*wr[2][c]
                            + f3*wr[3][c] + f4*wr[4][c] + f5*wr[5][c];
            pk[c] = (short)f2bf(silu_f(a));
        }
        int p = j16 ^ (m & 7);
        *(bf16x8*)(lA + m * 256 + p * 16) = pk;
    }

    __syncthreads();

    // ---- phase 2: P prefetch (overlaps MFMA), then MFMA ----
    unsigned short q1[2][4][4], q2[2][4][4];
#pragma unroll
    for (int mi = 0; mi < 2; ++mi)
#pragma unroll
        for (int r = 0; r < 4; ++r) {
            const unsigned short* p1r = P1 + ti[mi * 4 + r] * 128;
            const unsigned short* p2r = P2 + tj[mi * 4 + r] * 128;
#pragma unroll
            for (int ni = 0; ni < 4; ++ni) {
                int o = wn + ni * 16 + l15;
                q1[mi][r][ni] = p1r[o];
                q2[mi][r][ni] = p2r[o];
            }
        }

    f32x4 acc[2][4] = {};
    const int l7 = l15 & 7;
#pragma unroll
    for (int ks = 0; ks < 4; ++ks) {
        const int j = ks * 4 + quad;
        const int p = j ^ l7;
        bf16x8 af[2], bfv[4];
#pragma unroll
        for (int mi = 0; mi < 2; ++mi)
            af[mi] = *(const bf16x8*)(lA + (wm + mi * 16 + l15) * 256 + p * 16);
#pragma unroll
        for (int ni = 0; ni < 4; ++ni)
            bfv[ni] = *(const bf16x8*)(lB + (wn + ni * 16 + l15) * 256 + p * 16);
#pragma unroll
        for (int mi = 0; mi < 2; ++mi)
#pragma unroll
            for (int ni = 0; ni < 4; ++ni)
                acc[mi][ni] = __builtin_amdgcn_mfma_f32_16x16x32_bf16(
                    af[mi], bfv[ni], acc[mi][ni], 0, 0, 0);
    }

    // ---- phase 3: epilogue ----
#pragma unroll
    for (int mi = 0; mi < 2; ++mi)
#pragma unroll
        for (int r = 0; r < 4; ++r) {
            int m = wm + mi * 16 + quad * 4 + r;
            size_t e = e0 + m;
#pragma unroll
            for (int ni = 0; ni < 4; ++ni) {
                int o = wn + ni * 16 + l15;
                float v = acc[mi][ni][r] + bf2f(q1[mi][r][ni]) + bf2f(q2[mi][r][ni]);
                out[e * 128 + o] = silu_f(v);
            }
        }
}

extern "C" void kernel_launch(void* const* d_in, const int* in_sizes, int n_in,
                              void* d_out, int out_size, void* d_ws, size_t ws_size,
                              hipStream_t stream) {
    const int*   x        = (const int*)d_in[0];
    const float* rbf      = (const float*)d_in[1];
    const int*   ei       = (const int*)d_in[2];
    const int*   ej       = (const int*)d_in[3];
    const int*   code_idx = (const int*)d_in[4];
    const float* codebook = (const float*)d_in[5];
    const float* W_rbf    = (const float*)d_in[6];
    const float* b_rbf    = (const float*)d_in[7];
    const float* W        = (const float*)d_in[8];
    const float* b        = (const float*)d_in[9];
    float* out = (float*)d_out;

    const int nE = in_sizes[2];                   // 160000

    if (ws_size < 98304) return;                  // P1 + P2 + Wt3, bf16
    unsigned short* P1  = (unsigned short*)d_ws;  // 32 KB
    unsigned short* P2  = P1 + 16384;             // 32 KB
    unsigned short* Wt3 = P2 + 16384;             // 32 KB

    prep_P<<<128, 256, 0, stream>>>(code_idx, codebook, W, b, P1, P2, Wt3);
    fused_main<<<nE / 64, 256, 0, stream>>>(x, rbf, ei, ej, W_rbf, b_rbf,
                                            P1, P2, Wt3, out);
}